// Round 3
// baseline (64.475 us; speedup 1.0000x reference)
//
#include <hip/hip_runtime.h>
#include <math.h>

#define N 512
#define D 256
#define LOSS_MARGIN 0.3f
#define STRIDE 260   // 256+4 floats: 16B-aligned rows; rows r,r+8 alias -> 2-way (free)

// k1: grid (16,16), block 256. Tile = 32 anchors (LDS) x 32 candidates (global/L2).
// Thread (il=t&15, jl=t>>4) computes 2x2 distances: anchors {il,il+16}, cands {jl,jl+16}.
__global__ __launch_bounds__(256) void triplet_tile_kernel(
    const float* __restrict__ X,    // (512,256)
    const int*  __restrict__ tgt,   // (512,)
    float* __restrict__ wap,        // (16,512) per-jtile hardest-positive
    float* __restrict__ wan)        // (16,512) per-jtile hardest-negative
{
    const int it = blockIdx.x, jt = blockIdx.y, t = threadIdx.x;
    const int i0 = it * 32, j0 = jt * 32;

    __shared__ float xi[32 * STRIDE];          // 33.3 KB
    __shared__ float sap[4][32], san[4][32];

    // Stage 32 anchor rows into LDS, fully coalesced float4 loads.
    #pragma unroll
    for (int k = 0; k < 8; ++k) {
        const int f = t + 256 * k;             // 0..2047 float4 slots
        const int r = f >> 6, c = (f & 63) << 2;
        *(float4*)&xi[r * STRIDE + c] = *(const float4*)(X + (i0 + r) * D + c);
    }
    __syncthreads();

    const int il = t & 15, jl = t >> 4;
    const int ci0 = tgt[i0 + il], ci1 = tgt[i0 + il + 16];
    const int cj0 = tgt[j0 + jl], cj1 = tgt[j0 + jl + 16];

    const float4* a0p = (const float4*)&xi[il * STRIDE];
    const float4* a1p = (const float4*)&xi[(il + 16) * STRIDE];
    const float4* b0p = (const float4*)(X + (j0 + jl) * D);        // L2-resident
    const float4* b1p = (const float4*)(X + (j0 + jl + 16) * D);

    float4 s00 = {0,0,0,0}, s01 = {0,0,0,0}, s10 = {0,0,0,0}, s11 = {0,0,0,0};
    #pragma unroll 4
    for (int d = 0; d < D / 4; ++d) {
        const float4 a0 = a0p[d], a1 = a1p[d];   // LDS: 2-way max (free)
        const float4 b0 = b0p[d], b1 = b1p[d];   // VMEM: 4 lines + 16-lane bcast
        s00.x += fabsf(a0.x-b0.x); s00.y += fabsf(a0.y-b0.y);
        s00.z += fabsf(a0.z-b0.z); s00.w += fabsf(a0.w-b0.w);
        s01.x += fabsf(a0.x-b1.x); s01.y += fabsf(a0.y-b1.y);
        s01.z += fabsf(a0.z-b1.z); s01.w += fabsf(a0.w-b1.w);
        s10.x += fabsf(a1.x-b0.x); s10.y += fabsf(a1.y-b0.y);
        s10.z += fabsf(a1.z-b0.z); s10.w += fabsf(a1.w-b0.w);
        s11.x += fabsf(a1.x-b1.x); s11.y += fabsf(a1.y-b1.y);
        s11.z += fabsf(a1.z-b1.z); s11.w += fabsf(a1.w-b1.w);
    }
    const float inv = 1.0f / (float)D;
    const float d00 = (s00.x+s00.y+s00.z+s00.w) * inv;
    const float d01 = (s01.x+s01.y+s01.z+s01.w) * inv;
    const float d10 = (s10.x+s10.y+s10.z+s10.w) * inv;
    const float d11 = (s11.x+s11.y+s11.z+s11.w) * inv;

    float ap0 = fmaxf(cj0==ci0 ? d00 : -INFINITY, cj1==ci0 ? d01 : -INFINITY);
    float an0 = fminf(cj0==ci0 ?  INFINITY : d00, cj1==ci0 ?  INFINITY : d01);
    float ap1 = fmaxf(cj0==ci1 ? d10 : -INFINITY, cj1==ci1 ? d11 : -INFINITY);
    float an1 = fminf(cj0==ci1 ?  INFINITY : d10, cj1==ci1 ?  INFINITY : d11);

    // Reduce over the 4 jl values resident in this wave (lanes differ in bits 4-5).
    ap0 = fmaxf(ap0, __shfl_xor(ap0, 16, 64)); an0 = fminf(an0, __shfl_xor(an0, 16, 64));
    ap1 = fmaxf(ap1, __shfl_xor(ap1, 16, 64)); an1 = fminf(an1, __shfl_xor(an1, 16, 64));
    ap0 = fmaxf(ap0, __shfl_xor(ap0, 32, 64)); an0 = fminf(an0, __shfl_xor(an0, 32, 64));
    ap1 = fmaxf(ap1, __shfl_xor(ap1, 32, 64)); an1 = fminf(an1, __shfl_xor(an1, 32, 64));

    const int w = t >> 6, wl = t & 63;
    if (wl < 16) {
        sap[w][wl]      = ap0;  san[w][wl]      = an0;   // anchor il
        sap[w][wl + 16] = ap1;  san[w][wl + 16] = an1;   // anchor il+16
    }
    __syncthreads();

    if (t < 32) {
        const float A  = fmaxf(fmaxf(sap[0][t], sap[1][t]), fmaxf(sap[2][t], sap[3][t]));
        const float Nn = fminf(fminf(san[0][t], san[1][t]), fminf(san[2][t], san[3][t]));
        wap[jt * N + i0 + t] = A;
        wan[jt * N + i0 + t] = Nn;
    }
}

// k2: one block, 512 threads — combine 16 j-tile partials per row, hinge, mean.
__global__ __launch_bounds__(512) void triplet_final_kernel(
    const float* __restrict__ wap, const float* __restrict__ wan,
    float* __restrict__ out)
{
    const int t = threadIdx.x;   // row 0..511
    float ap = -INFINITY, an = INFINITY;
    #pragma unroll
    for (int jt = 0; jt < 16; ++jt) {
        ap = fmaxf(ap, wap[jt * N + t]);
        an = fminf(an, wan[jt * N + t]);
    }
    float v = fmaxf(ap - an + LOSS_MARGIN, 0.0f);
    #pragma unroll
    for (int off = 32; off >= 1; off >>= 1) v += __shfl_down(v, off, 64);
    __shared__ float s[8];
    if ((t & 63) == 0) s[t >> 6] = v;
    __syncthreads();
    if (t == 0) {
        float tot = 0.f;
        #pragma unroll
        for (int w = 0; w < 8; ++w) tot += s[w];
        out[0] = tot * (1.0f / (float)N);
    }
}

extern "C" void kernel_launch(void* const* d_in, const int* in_sizes, int n_in,
                              void* d_out, int out_size, void* d_ws, size_t ws_size,
                              hipStream_t stream) {
    const float* X   = (const float*)d_in[0];
    const int*   tgt = (const int*)d_in[1];
    float* out = (float*)d_out;
    float* wap = (float*)d_ws;
    float* wan = wap + 16 * N;

    dim3 grid(16, 16);
    triplet_tile_kernel<<<grid, 256, 0, stream>>>(X, tgt, wap, wan);
    triplet_final_kernel<<<1, N, 0, stream>>>(wap, wan, out);
}